// Round 1
// baseline (883.597 us; speedup 1.0000x reference)
//
#include <hip/hip_runtime.h>
#include <math.h>

#define BB 2
#define LL 2
#define SS 2048
#define DD 512
#define HH 8
#define DHH 64
#define BLBL (BB*LL)
#define RR (BLBL*SS)   // 8192 rows

// ---------------------------------------------------------------
// K0: RoPE table (fp64 -> fp32). 2048 positions x 32 freqs.
// ---------------------------------------------------------------
__global__ void rope_table_kernel(float* __restrict__ cos_t, float* __restrict__ sin_t) {
    int idx = blockIdx.x * 256 + threadIdx.x;
    if (idx >= SS * 32) return;
    int s = idx >> 5;
    int f = idx & 31;
    double inv = pow(10000.0, -(double)(2 * f) / (double)DHH);
    double ang = (double)s * inv;
    cos_t[idx] = (float)cos(ang);
    sin_t[idx] = (float)sin(ang);
}

// ---------------------------------------------------------------
// K1: QKV projection GEMM (C = X * W^T + b), fused RoPE + permute.
//  X: [8192, 512] row-major.  W*: [512, 512] row-major (dot over dim 1).
//  Outputs in [bl, h, s, dh] layout:
//    qm = rotary(q_proj), km = rotary(v_proj), vm = k_proj
// Tile: BM=128, BN=128, BK=16; 256 threads; 8x8 microtile.
// ---------------------------------------------------------------
#define BM 128
#define BN 128
#define BK 16

__global__ __launch_bounds__(256) void qkv_rope_kernel(
    const float* __restrict__ X,
    const float* __restrict__ Wq, const float* __restrict__ bq,
    const float* __restrict__ Wk, const float* __restrict__ bk,
    const float* __restrict__ Wv, const float* __restrict__ bv,
    const float* __restrict__ cos_t, const float* __restrict__ sin_t,
    float* __restrict__ qm, float* __restrict__ km, float* __restrict__ vm)
{
    __shared__ float As[BK][BM + 4];
    __shared__ float Bs[BK][BN + 4];

    const int tid = threadIdx.x;
    const int tx = tid & 15;
    const int ty = tid >> 4;
    const int n0 = blockIdx.x * BN;   // 0..1535, col in concatenated [q|k|v]
    const int r0 = blockIdx.y * BM;

    const float* Wsel;
    const float* bsel;
    int nloc0;
    int mat;
    if (n0 < 512)       { Wsel = Wq; bsel = bq; mat = 0; nloc0 = n0; }
    else if (n0 < 1024) { Wsel = Wk; bsel = bk; mat = 1; nloc0 = n0 - 512; }
    else                { Wsel = Wv; bsel = bv; mat = 2; nloc0 = n0 - 1024; }

    float acc[8][8];
    #pragma unroll
    for (int i = 0; i < 8; ++i)
        #pragma unroll
        for (int j = 0; j < 8; ++j) acc[i][j] = 0.f;

    for (int k0 = 0; k0 < DD; k0 += BK) {
        __syncthreads();
        #pragma unroll
        for (int it = 0; it < 2; ++it) {
            int idx = tid + it * 256;        // 0..511
            int row = idx >> 2;              // 0..127
            int c   = idx & 3;               // float4 index within 16 k's
            float4 a = *(const float4*)&X[(size_t)(r0 + row) * DD + k0 + c * 4];
            As[c * 4 + 0][row] = a.x;
            As[c * 4 + 1][row] = a.y;
            As[c * 4 + 2][row] = a.z;
            As[c * 4 + 3][row] = a.w;
            float4 w = *(const float4*)&Wsel[(size_t)(nloc0 + row) * DD + k0 + c * 4];
            Bs[c * 4 + 0][row] = w.x;
            Bs[c * 4 + 1][row] = w.y;
            Bs[c * 4 + 2][row] = w.z;
            Bs[c * 4 + 3][row] = w.w;
        }
        __syncthreads();
        #pragma unroll
        for (int kk = 0; kk < BK; ++kk) {
            float4 a0 = *(const float4*)&As[kk][ty * 4];
            float4 a1 = *(const float4*)&As[kk][64 + ty * 4];
            float4 b0 = *(const float4*)&Bs[kk][tx * 4];
            float4 b1 = *(const float4*)&Bs[kk][64 + tx * 4];
            float av[8] = {a0.x, a0.y, a0.z, a0.w, a1.x, a1.y, a1.z, a1.w};
            float bw[8] = {b0.x, b0.y, b0.z, b0.w, b1.x, b1.y, b1.z, b1.w};
            #pragma unroll
            for (int i = 0; i < 8; ++i)
                #pragma unroll
                for (int j = 0; j < 8; ++j)
                    acc[i][j] = fmaf(av[i], bw[j], acc[i][j]);
        }
    }

    // Epilogue: bias + (maybe) rotary + permuted store.
    #pragma unroll
    for (int ri = 0; ri < 2; ++ri) {
        #pragma unroll
        for (int i = 0; i < 4; ++i) {
            int r  = r0 + ri * 64 + ty * 4 + i;
            int bl = r >> 11;       // / 2048
            int s  = r & 2047;
            #pragma unroll
            for (int ci = 0; ci < 2; ++ci) {
                int nl  = nloc0 + ci * 64 + tx * 4;  // within-matrix col, 4-aligned
                int h   = nl >> 6;
                int dh0 = nl & 63;
                float v0 = acc[ri * 4 + i][ci * 4 + 0] + bsel[nl + 0];
                float v1 = acc[ri * 4 + i][ci * 4 + 1] + bsel[nl + 1];
                float v2 = acc[ri * 4 + i][ci * 4 + 2] + bsel[nl + 2];
                float v3 = acc[ri * 4 + i][ci * 4 + 3] + bsel[nl + 3];
                float4 o;
                if (mat == 1) {
                    // k_proj -> v_mat, no rotary
                    o = make_float4(v0, v1, v2, v3);
                } else {
                    int f0 = dh0 >> 1;           // freq index of first pair
                    float c0 = cos_t[s * 32 + f0],     s0 = sin_t[s * 32 + f0];
                    float c1 = cos_t[s * 32 + f0 + 1], s1 = sin_t[s * 32 + f0 + 1];
                    o.x = v0 * c0 - v1 * s0;
                    o.y = v1 * c0 + v0 * s0;
                    o.z = v2 * c1 - v3 * s1;
                    o.w = v3 * c1 + v2 * s1;
                }
                float* dst = (mat == 0) ? qm : (mat == 1 ? vm : km);
                size_t di = ((size_t)(bl * HH + h) * SS + s) * DHH + dh0;
                *(float4*)&dst[di] = o;
            }
        }
    }
}

// ---------------------------------------------------------------
// K2: causal flash attention, fp32. One block = 64 queries of one
// (bl, h). Online softmax; 4x4 register tiles; LDS round-trip for P.
// ---------------------------------------------------------------
__global__ __launch_bounds__(256) void attn_kernel(
    const float* __restrict__ qm, const float* __restrict__ km,
    const float* __restrict__ vm, float* __restrict__ inter)
{
    __shared__ float Qs[64][68];   // [dh][q]  (transposed)
    __shared__ float Ks[64][68];   // [dh][k]  (transposed)
    __shared__ float Vs[64][68];   // [k][dh]
    __shared__ float Ps[64][68];   // [q][k]

    const int tid = threadIdx.x;
    const int tx = tid & 15;
    const int ty = tid >> 4;
    const int qt = blockIdx.x;
    const int h  = blockIdx.y;
    const int bl = blockIdx.z;
    const size_t base = ((size_t)(bl * HH + h)) * SS * DHH;
    const int q0 = qt * 64;
    const float scale = 0.04419417382415922f;  // 1/sqrt(512)

    // Load Q tile transposed, pre-scaled.
    #pragma unroll
    for (int it = 0; it < 4; ++it) {
        int idx = tid + it * 256;     // 0..1023
        int row = idx >> 4;           // 0..63
        int c   = idx & 15;
        float4 v = *(const float4*)&qm[base + (size_t)(q0 + row) * DHH + c * 4];
        Qs[c * 4 + 0][row] = v.x * scale;
        Qs[c * 4 + 1][row] = v.y * scale;
        Qs[c * 4 + 2][row] = v.z * scale;
        Qs[c * 4 + 3][row] = v.w * scale;
    }

    float m_i[4], l_i[4], o[4][4];
    #pragma unroll
    for (int i = 0; i < 4; ++i) {
        m_i[i] = -INFINITY;
        l_i[i] = 0.f;
        #pragma unroll
        for (int j = 0; j < 4; ++j) o[i][j] = 0.f;
    }

    for (int kt = 0; kt <= qt; ++kt) {
        __syncthreads();   // protect Ks/Vs/Ps against previous iteration readers
        int k0 = kt * 64;
        #pragma unroll
        for (int it = 0; it < 4; ++it) {
            int idx = tid + it * 256;
            int row = idx >> 4;
            int c   = idx & 15;
            float4 kv = *(const float4*)&km[base + (size_t)(k0 + row) * DHH + c * 4];
            Ks[c * 4 + 0][row] = kv.x;
            Ks[c * 4 + 1][row] = kv.y;
            Ks[c * 4 + 2][row] = kv.z;
            Ks[c * 4 + 3][row] = kv.w;
            float4 vv = *(const float4*)&vm[base + (size_t)(k0 + row) * DHH + c * 4];
            *(float4*)&Vs[row][c * 4] = vv;
        }
        __syncthreads();

        // S = (scaled Q) K^T   -- 4x4 per thread
        float sc[4][4];
        #pragma unroll
        for (int i = 0; i < 4; ++i)
            #pragma unroll
            for (int j = 0; j < 4; ++j) sc[i][j] = 0.f;
        #pragma unroll 8
        for (int kk = 0; kk < 64; ++kk) {
            float4 a = *(const float4*)&Qs[kk][ty * 4];
            float4 b = *(const float4*)&Ks[kk][tx * 4];
            float av[4] = {a.x, a.y, a.z, a.w};
            float bw[4] = {b.x, b.y, b.z, b.w};
            #pragma unroll
            for (int i = 0; i < 4; ++i)
                #pragma unroll
                for (int j = 0; j < 4; ++j)
                    sc[i][j] = fmaf(av[i], bw[j], sc[i][j]);
        }

        if (kt == qt) {
            #pragma unroll
            for (int i = 0; i < 4; ++i)
                #pragma unroll
                for (int j = 0; j < 4; ++j)
                    if (tx * 4 + j > ty * 4 + i) sc[i][j] = -INFINITY;
        }

        // Row max across the 16 tx lanes.
        float mx[4];
        #pragma unroll
        for (int i = 0; i < 4; ++i) {
            float m = fmaxf(fmaxf(sc[i][0], sc[i][1]), fmaxf(sc[i][2], sc[i][3]));
            #pragma unroll
            for (int off = 8; off; off >>= 1)
                m = fmaxf(m, __shfl_xor(m, off, 16));
            mx[i] = m;
        }

        float alpha[4];
        #pragma unroll
        for (int i = 0; i < 4; ++i) {
            float mnew = fmaxf(m_i[i], mx[i]);
            alpha[i] = __expf(m_i[i] - mnew);
            m_i[i] = mnew;
        }

        float rs[4];
        #pragma unroll
        for (int i = 0; i < 4; ++i) {
            float r = 0.f;
            #pragma unroll
            for (int j = 0; j < 4; ++j) {
                float p = __expf(sc[i][j] - m_i[i]);
                sc[i][j] = p;
                r += p;
            }
            #pragma unroll
            for (int off = 8; off; off >>= 1)
                r += __shfl_xor(r, off, 16);
            rs[i] = r;
        }

        #pragma unroll
        for (int i = 0; i < 4; ++i) {
            l_i[i] = l_i[i] * alpha[i] + rs[i];
            #pragma unroll
            for (int j = 0; j < 4; ++j) o[i][j] *= alpha[i];
        }

        // P to LDS (natural [q][k] layout)
        #pragma unroll
        for (int i = 0; i < 4; ++i) {
            float4 p4 = make_float4(sc[i][0], sc[i][1], sc[i][2], sc[i][3]);
            *(float4*)&Ps[ty * 4 + i][tx * 4] = p4;
        }
        __syncthreads();

        // O += P V
        #pragma unroll 4
        for (int kk0 = 0; kk0 < 64; kk0 += 4) {
            float4 pv4[4];
            #pragma unroll
            for (int i = 0; i < 4; ++i)
                pv4[i] = *(const float4*)&Ps[ty * 4 + i][kk0];
            float4 vv4[4];
            #pragma unroll
            for (int q = 0; q < 4; ++q)
                vv4[q] = *(const float4*)&Vs[kk0 + q][tx * 4];
            #pragma unroll
            for (int i = 0; i < 4; ++i) {
                float pw[4] = {pv4[i].x, pv4[i].y, pv4[i].z, pv4[i].w};
                #pragma unroll
                for (int q = 0; q < 4; ++q) {
                    float vw[4] = {vv4[q].x, vv4[q].y, vv4[q].z, vv4[q].w};
                    #pragma unroll
                    for (int j = 0; j < 4; ++j)
                        o[i][j] = fmaf(pw[q], vw[j], o[i][j]);
                }
            }
        }
    }

    // Epilogue: normalize, store to inter [bl, s, h*dh]
    #pragma unroll
    for (int i = 0; i < 4; ++i) {
        float inv_l = 1.f / l_i[i];
        int srow = q0 + ty * 4 + i;
        size_t di = ((size_t)bl * SS + srow) * DD + h * DHH + tx * 4;
        float4 o4 = make_float4(o[i][0] * inv_l, o[i][1] * inv_l,
                                o[i][2] * inv_l, o[i][3] * inv_l);
        *(float4*)&inter[di] = o4;
    }
}

// ---------------------------------------------------------------
// K3: output projection  out = inter * Wo^T + bo
// ---------------------------------------------------------------
__global__ __launch_bounds__(256) void outproj_kernel(
    const float* __restrict__ A, const float* __restrict__ Wo,
    const float* __restrict__ bo, float* __restrict__ out)
{
    __shared__ float As[BK][BM + 4];
    __shared__ float Bs[BK][BN + 4];

    const int tid = threadIdx.x;
    const int tx = tid & 15;
    const int ty = tid >> 4;
    const int n0 = blockIdx.x * BN;   // 0..511
    const int r0 = blockIdx.y * BM;

    float acc[8][8];
    #pragma unroll
    for (int i = 0; i < 8; ++i)
        #pragma unroll
        for (int j = 0; j < 8; ++j) acc[i][j] = 0.f;

    for (int k0 = 0; k0 < DD; k0 += BK) {
        __syncthreads();
        #pragma unroll
        for (int it = 0; it < 2; ++it) {
            int idx = tid + it * 256;
            int row = idx >> 2;
            int c   = idx & 3;
            float4 a = *(const float4*)&A[(size_t)(r0 + row) * DD + k0 + c * 4];
            As[c * 4 + 0][row] = a.x;
            As[c * 4 + 1][row] = a.y;
            As[c * 4 + 2][row] = a.z;
            As[c * 4 + 3][row] = a.w;
            float4 w = *(const float4*)&Wo[(size_t)(n0 + row) * DD + k0 + c * 4];
            Bs[c * 4 + 0][row] = w.x;
            Bs[c * 4 + 1][row] = w.y;
            Bs[c * 4 + 2][row] = w.z;
            Bs[c * 4 + 3][row] = w.w;
        }
        __syncthreads();
        #pragma unroll
        for (int kk = 0; kk < BK; ++kk) {
            float4 a0 = *(const float4*)&As[kk][ty * 4];
            float4 a1 = *(const float4*)&As[kk][64 + ty * 4];
            float4 b0 = *(const float4*)&Bs[kk][tx * 4];
            float4 b1 = *(const float4*)&Bs[kk][64 + tx * 4];
            float av[8] = {a0.x, a0.y, a0.z, a0.w, a1.x, a1.y, a1.z, a1.w};
            float bw[8] = {b0.x, b0.y, b0.z, b0.w, b1.x, b1.y, b1.z, b1.w};
            #pragma unroll
            for (int i = 0; i < 8; ++i)
                #pragma unroll
                for (int j = 0; j < 8; ++j)
                    acc[i][j] = fmaf(av[i], bw[j], acc[i][j]);
        }
    }

    #pragma unroll
    for (int ri = 0; ri < 2; ++ri) {
        #pragma unroll
        for (int i = 0; i < 4; ++i) {
            int r = r0 + ri * 64 + ty * 4 + i;
            #pragma unroll
            for (int ci = 0; ci < 2; ++ci) {
                int n = n0 + ci * 64 + tx * 4;
                float4 o;
                o.x = acc[ri * 4 + i][ci * 4 + 0] + bo[n + 0];
                o.y = acc[ri * 4 + i][ci * 4 + 1] + bo[n + 1];
                o.z = acc[ri * 4 + i][ci * 4 + 2] + bo[n + 2];
                o.w = acc[ri * 4 + i][ci * 4 + 3] + bo[n + 3];
                *(float4*)&out[(size_t)r * DD + n] = o;
            }
        }
    }
}

// ---------------------------------------------------------------
extern "C" void kernel_launch(void* const* d_in, const int* in_sizes, int n_in,
                              void* d_out, int out_size, void* d_ws, size_t ws_size,
                              hipStream_t stream)
{
    const float* x  = (const float*)d_in[0];
    const float* Wq = (const float*)d_in[1];
    const float* bq = (const float*)d_in[2];
    const float* Wk = (const float*)d_in[3];
    const float* bk = (const float*)d_in[4];
    const float* Wv = (const float*)d_in[5];
    const float* bv = (const float*)d_in[6];
    const float* Wo = (const float*)d_in[7];
    const float* bo = (const float*)d_in[8];
    float* out = (float*)d_out;
    float* ws  = (float*)d_ws;

    // Workspace layout (floats):
    float* qm    = ws;                 //  4,194,304  rotary(q_proj)   [bl,h,s,dh]
    float* km    = ws + 4194304;       //  4,194,304  rotary(v_proj)   [bl,h,s,dh]
    float* vm    = ws + 8388608;       //  4,194,304  k_proj           [bl,h,s,dh]
    float* inter = ws + 12582912;      //  4,194,304  attn out         [bl,s,e]
    float* cos_t = ws + 16777216;      //  65,536
    float* sin_t = ws + 16842752;      //  65,536
    // total 16,908,288 floats = 67.6 MB

    rope_table_kernel<<<dim3(256), dim3(256), 0, stream>>>(cos_t, sin_t);
    qkv_rope_kernel<<<dim3(12, 64), dim3(256), 0, stream>>>(
        x, Wq, bq, Wk, bk, Wv, bv, cos_t, sin_t, qm, km, vm);
    attn_kernel<<<dim3(32, 8, 4), dim3(256), 0, stream>>>(qm, km, vm, inter);
    outproj_kernel<<<dim3(4, 64), dim3(256), 0, stream>>>(inter, Wo, bo, out);
}

// Round 2
// 374.261 us; speedup vs baseline: 2.3609x; 2.3609x over previous
//
#include <hip/hip_runtime.h>
#include <math.h>

#define BB 2
#define LL 2
#define SS 2048
#define DD 512
#define HH 8
#define DHH 64

typedef __attribute__((ext_vector_type(8))) short bf16x8;
typedef __attribute__((ext_vector_type(4))) float f32x4;

#define MFMA16(a, b, c) __builtin_amdgcn_mfma_f32_16x16x32_bf16((a), (b), (c), 0, 0, 0)

__device__ __forceinline__ unsigned short f2bf(float f) {
    union { float f; unsigned u; } x; x.f = f;
    unsigned u = x.u;
    return (unsigned short)((u + 0x7fffu + ((u >> 16) & 1u)) >> 16);
}

// ---------------------------------------------------------------
// K0: RoPE table (fp64 -> fp32). 2048 positions x 32 freqs.
// ---------------------------------------------------------------
__global__ void rope_table_kernel(float* __restrict__ cos_t, float* __restrict__ sin_t) {
    int idx = blockIdx.x * 256 + threadIdx.x;
    if (idx >= SS * 32) return;
    int s = idx >> 5;
    int f = idx & 31;
    double inv = pow(10000.0, -(double)(2 * f) / (double)DHH);
    double ang = (double)s * inv;
    cos_t[idx] = (float)cos(ang);
    sin_t[idx] = (float)sin(ang);
}

// ---------------------------------------------------------------
// K1: QKV projection GEMM (C = X * W^T + b), fused RoPE + permute.
// Outputs (bf16):
//   qm [bl,h,s,dh] = rotary(q_proj) * 1/sqrt(512)
//   km [bl,h,s,dh] = rotary(v_proj)          (attention "K")
//   vt [bl,h,dh,s] = k_proj, transposed      (attention "V", key-contiguous)
// ---------------------------------------------------------------
#define BM 128
#define BN 128
#define BK 16

__global__ __launch_bounds__(256) void qkv_rope_kernel(
    const float* __restrict__ X,
    const float* __restrict__ Wq, const float* __restrict__ bq,
    const float* __restrict__ Wk, const float* __restrict__ bk,
    const float* __restrict__ Wv, const float* __restrict__ bv,
    const float* __restrict__ cos_t, const float* __restrict__ sin_t,
    unsigned short* __restrict__ qm, unsigned short* __restrict__ km,
    unsigned short* __restrict__ vt)
{
    __shared__ float As[BK][BM + 4];
    __shared__ float Bs[BK][BN + 4];

    const int tid = threadIdx.x;
    const int tx = tid & 15;
    const int ty = tid >> 4;
    const int n0 = blockIdx.x * BN;   // 0..1535, col in concatenated [q|k|v]
    const int r0 = blockIdx.y * BM;
    const float scale = 0.04419417382415922f;  // 1/sqrt(512)

    const float* Wsel;
    const float* bsel;
    int nloc0;
    int mat;
    if (n0 < 512)       { Wsel = Wq; bsel = bq; mat = 0; nloc0 = n0; }
    else if (n0 < 1024) { Wsel = Wk; bsel = bk; mat = 1; nloc0 = n0 - 512; }
    else                { Wsel = Wv; bsel = bv; mat = 2; nloc0 = n0 - 1024; }

    float acc[8][8];
    #pragma unroll
    for (int i = 0; i < 8; ++i)
        #pragma unroll
        for (int j = 0; j < 8; ++j) acc[i][j] = 0.f;

    for (int k0 = 0; k0 < DD; k0 += BK) {
        __syncthreads();
        #pragma unroll
        for (int it = 0; it < 2; ++it) {
            int idx = tid + it * 256;
            int row = idx >> 2;
            int c   = idx & 3;
            float4 a = *(const float4*)&X[(size_t)(r0 + row) * DD + k0 + c * 4];
            As[c * 4 + 0][row] = a.x;
            As[c * 4 + 1][row] = a.y;
            As[c * 4 + 2][row] = a.z;
            As[c * 4 + 3][row] = a.w;
            float4 w = *(const float4*)&Wsel[(size_t)(nloc0 + row) * DD + k0 + c * 4];
            Bs[c * 4 + 0][row] = w.x;
            Bs[c * 4 + 1][row] = w.y;
            Bs[c * 4 + 2][row] = w.z;
            Bs[c * 4 + 3][row] = w.w;
        }
        __syncthreads();
        #pragma unroll
        for (int kk = 0; kk < BK; ++kk) {
            float4 a0 = *(const float4*)&As[kk][ty * 4];
            float4 a1 = *(const float4*)&As[kk][64 + ty * 4];
            float4 b0 = *(const float4*)&Bs[kk][tx * 4];
            float4 b1 = *(const float4*)&Bs[kk][64 + tx * 4];
            float av[8] = {a0.x, a0.y, a0.z, a0.w, a1.x, a1.y, a1.z, a1.w};
            float bw[8] = {b0.x, b0.y, b0.z, b0.w, b1.x, b1.y, b1.z, b1.w};
            #pragma unroll
            for (int i = 0; i < 8; ++i)
                #pragma unroll
                for (int j = 0; j < 8; ++j)
                    acc[i][j] = fmaf(av[i], bw[j], acc[i][j]);
        }
    }

    #pragma unroll
    for (int ri = 0; ri < 2; ++ri) {
        #pragma unroll
        for (int i = 0; i < 4; ++i) {
            int r  = r0 + ri * 64 + ty * 4 + i;
            int bl = r >> 11;
            int s  = r & 2047;
            #pragma unroll
            for (int ci = 0; ci < 2; ++ci) {
                int nl  = nloc0 + ci * 64 + tx * 4;
                int h   = nl >> 6;
                int dh0 = nl & 63;
                float v0 = acc[ri * 4 + i][ci * 4 + 0] + bsel[nl + 0];
                float v1 = acc[ri * 4 + i][ci * 4 + 1] + bsel[nl + 1];
                float v2 = acc[ri * 4 + i][ci * 4 + 2] + bsel[nl + 2];
                float v3 = acc[ri * 4 + i][ci * 4 + 3] + bsel[nl + 3];
                if (mat == 1) {
                    // k_proj -> attention V, transposed [bl,h,dh,s]
                    size_t tb = ((size_t)(bl * HH + h) * DHH + dh0) * SS + s;
                    vt[tb]          = f2bf(v0);
                    vt[tb + SS]     = f2bf(v1);
                    vt[tb + 2 * SS] = f2bf(v2);
                    vt[tb + 3 * SS] = f2bf(v3);
                } else {
                    int f0 = dh0 >> 1;
                    float c0 = cos_t[s * 32 + f0],     s0 = sin_t[s * 32 + f0];
                    float c1 = cos_t[s * 32 + f0 + 1], s1 = sin_t[s * 32 + f0 + 1];
                    float o0 = v0 * c0 - v1 * s0;
                    float o1 = v1 * c0 + v0 * s0;
                    float o2 = v2 * c1 - v3 * s1;
                    float o3 = v3 * c1 + v2 * s1;
                    if (mat == 0) { o0 *= scale; o1 *= scale; o2 *= scale; o3 *= scale; }
                    unsigned short* dst = (mat == 0) ? qm : km;
                    ushort4 pk;
                    pk.x = f2bf(o0); pk.y = f2bf(o1); pk.z = f2bf(o2); pk.w = f2bf(o3);
                    *(ushort4*)&dst[((size_t)(bl * HH + h) * SS + s) * DHH + dh0] = pk;
                }
            }
        }
    }
}

// ---------------------------------------------------------------
// K2: causal flash attention, bf16 MFMA (16x16x32).
// Block = 256 thr = 4 waves; Br=128 queries, Bc=64 keys.
// Softmax without max-subtraction (scores bounded by ~3.2).
// PV computed as O^T = V^T P^T; l via ones-row MFMA.
// ---------------------------------------------------------------
#define S_KV 72   // bf16 elems; 144 B rows, 16B aligned
#define S_P  72

__global__ __launch_bounds__(256) void attn_mfma_kernel(
    const unsigned short* __restrict__ qm,
    const unsigned short* __restrict__ km,
    const unsigned short* __restrict__ vt,
    float* __restrict__ inter)
{
    __shared__ unsigned short Ks[64 * S_KV];   // [key][dh]
    __shared__ unsigned short Vt[64 * S_KV];   // [dh][key]
    __shared__ unsigned short Ps[128 * S_P];   // [q_local][key], wave-private rows

    const int tid  = threadIdx.x;
    const int w    = tid >> 6;
    const int lane = tid & 63;
    const int c    = lane & 15;
    const int quad = lane >> 4;

    const int qt = (gridDim.x - 1) - blockIdx.x;   // heavy blocks first
    const int h  = blockIdx.y;
    const int bl = blockIdx.z;
    const int q0 = qt * 128;
    const int qw = q0 + w * 32;

    const size_t seq_base = (size_t)(bl * HH + h) * SS * DHH;  // qm, km
    const size_t vt_base  = (size_t)(bl * HH + h) * DHH * SS;  // vt [dh][s]

    // Q fragments (A-operand): [m-tile][k-step]
    bf16x8 qf[2][2];
    #pragma unroll
    for (int mt = 0; mt < 2; ++mt)
        #pragma unroll
        for (int kk = 0; kk < 2; ++kk)
            qf[mt][kk] = *(const bf16x8*)(qm + seq_base +
                (size_t)(qw + mt * 16 + c) * DHH + kk * 32 + quad * 8);

    f32x4 oacc[4][2];   // [dh-tile][q-tile], O^T layout
    f32x4 lacc[2];
    #pragma unroll
    for (int i = 0; i < 4; ++i)
        #pragma unroll
        for (int j = 0; j < 2; ++j)
            #pragma unroll
            for (int r = 0; r < 4; ++r) oacc[i][j][r] = 0.f;
    #pragma unroll
    for (int j = 0; j < 2; ++j)
        #pragma unroll
        for (int r = 0; r < 4; ++r) lacc[j][r] = 0.f;

    bf16x8 ones;
    #pragma unroll
    for (int i = 0; i < 8; ++i) ones[i] = (short)0x3F80;   // bf16 1.0

    const int ntiles = 2 * qt + 2;
    for (int kt = 0; kt < ntiles; ++kt) {
        __syncthreads();   // prev iter's Ks/Vt readers done
        {
            const unsigned short* kg = km + seq_base + (size_t)(kt * 64) * DHH;
            const unsigned short* vg = vt + vt_base + kt * 64;
            #pragma unroll
            for (int it = 0; it < 2; ++it) {
                int idx = tid + it * 256;        // 0..511
                int row = idx >> 3, ch = idx & 7;
                *(bf16x8*)&Ks[row * S_KV + ch * 8] = *(const bf16x8*)(kg + idx * 8);
                *(bf16x8*)&Vt[row * S_KV + ch * 8] =
                    *(const bf16x8*)(vg + (size_t)row * SS + ch * 8);
            }
        }
        __syncthreads();

        if (64 * kt <= qw + 31) {   // wave has at least one unmasked key
            // ---- S = Q K^T : 2x4 tiles of 16x16
            f32x4 sacc[2][4];
            #pragma unroll
            for (int mt = 0; mt < 2; ++mt)
                #pragma unroll
                for (int nt = 0; nt < 4; ++nt)
                    #pragma unroll
                    for (int r = 0; r < 4; ++r) sacc[mt][nt][r] = 0.f;
            #pragma unroll
            for (int kk = 0; kk < 2; ++kk) {
                bf16x8 bk[4];
                #pragma unroll
                for (int nt = 0; nt < 4; ++nt)
                    bk[nt] = *(const bf16x8*)&Ks[(nt * 16 + c) * S_KV + kk * 32 + quad * 8];
                #pragma unroll
                for (int mt = 0; mt < 2; ++mt)
                    #pragma unroll
                    for (int nt = 0; nt < 4; ++nt)
                        sacc[mt][nt] = MFMA16(qf[mt][kk], bk[nt], sacc[mt][nt]);
            }

            // ---- P = exp(S) (no max-sub; scores bounded), causal mask, to LDS bf16
            const bool need_mask = (64 * kt + 63 > qw);
            #pragma unroll
            for (int mt = 0; mt < 2; ++mt) {
                #pragma unroll
                for (int r = 0; r < 4; ++r) {
                    int prow = w * 32 + mt * 16 + quad * 4 + r;
                    int qrow = qw + mt * 16 + quad * 4 + r;
                    unsigned short* pp = &Ps[prow * S_P + c];
                    #pragma unroll
                    for (int nt = 0; nt < 4; ++nt) {
                        float p = __expf(sacc[mt][nt][r]);
                        if (need_mask && (64 * kt + nt * 16 + c > qrow)) p = 0.f;
                        pp[nt * 16] = f2bf(p);
                    }
                }
            }

            // ---- O^T += V^T P^T ; l += ones * P^T  (wave-private Ps: no barrier)
            #pragma unroll
            for (int kk = 0; kk < 2; ++kk) {
                bf16x8 bp0 = *(const bf16x8*)&Ps[(w * 32 + c) * S_P + kk * 32 + quad * 8];
                bf16x8 bp1 = *(const bf16x8*)&Ps[(w * 32 + 16 + c) * S_P + kk * 32 + quad * 8];
                lacc[0] = MFMA16(ones, bp0, lacc[0]);
                lacc[1] = MFMA16(ones, bp1, lacc[1]);
                #pragma unroll
                for (int mt4 = 0; mt4 < 4; ++mt4) {
                    bf16x8 av = *(const bf16x8*)&Vt[(mt4 * 16 + c) * S_KV + kk * 32 + quad * 8];
                    oacc[mt4][0] = MFMA16(av, bp0, oacc[mt4][0]);
                    oacc[mt4][1] = MFMA16(av, bp1, oacc[mt4][1]);
                }
            }
        }
    }

    // Epilogue: normalize, store O (float4) to inter [bl, s, h*dh]
    float invl0 = 1.f / lacc[0][0];
    float invl1 = 1.f / lacc[1][0];
    #pragma unroll
    for (int mt4 = 0; mt4 < 4; ++mt4) {
        int dh0 = mt4 * 16 + quad * 4;
        #pragma unroll
        for (int nt2 = 0; nt2 < 2; ++nt2) {
            int query = qw + nt2 * 16 + c;
            float il = nt2 ? invl1 : invl0;
            float4 o = make_float4(oacc[mt4][nt2][0] * il, oacc[mt4][nt2][1] * il,
                                   oacc[mt4][nt2][2] * il, oacc[mt4][nt2][3] * il);
            *(float4*)&inter[((size_t)bl * SS + query) * DD + h * DHH + dh0] = o;
        }
    }
}

// ---------------------------------------------------------------
// K3: output projection  out = inter * Wo^T + bo   (fp32)
// ---------------------------------------------------------------
__global__ __launch_bounds__(256) void outproj_kernel(
    const float* __restrict__ A, const float* __restrict__ Wo,
    const float* __restrict__ bo, float* __restrict__ out)
{
    __shared__ float As[BK][BM + 4];
    __shared__ float Bs[BK][BN + 4];

    const int tid = threadIdx.x;
    const int tx = tid & 15;
    const int ty = tid >> 4;
    const int n0 = blockIdx.x * BN;
    const int r0 = blockIdx.y * BM;

    float acc[8][8];
    #pragma unroll
    for (int i = 0; i < 8; ++i)
        #pragma unroll
        for (int j = 0; j < 8; ++j) acc[i][j] = 0.f;

    for (int k0 = 0; k0 < DD; k0 += BK) {
        __syncthreads();
        #pragma unroll
        for (int it = 0; it < 2; ++it) {
            int idx = tid + it * 256;
            int row = idx >> 2;
            int c   = idx & 3;
            float4 a = *(const float4*)&A[(size_t)(r0 + row) * DD + k0 + c * 4];
            As[c * 4 + 0][row] = a.x;
            As[c * 4 + 1][row] = a.y;
            As[c * 4 + 2][row] = a.z;
            As[c * 4 + 3][row] = a.w;
            float4 w = *(const float4*)&Wo[(size_t)(n0 + row) * DD + k0 + c * 4];
            Bs[c * 4 + 0][row] = w.x;
            Bs[c * 4 + 1][row] = w.y;
            Bs[c * 4 + 2][row] = w.z;
            Bs[c * 4 + 3][row] = w.w;
        }
        __syncthreads();
        #pragma unroll
        for (int kk = 0; kk < BK; ++kk) {
            float4 a0 = *(const float4*)&As[kk][ty * 4];
            float4 a1 = *(const float4*)&As[kk][64 + ty * 4];
            float4 b0 = *(const float4*)&Bs[kk][tx * 4];
            float4 b1 = *(const float4*)&Bs[kk][64 + tx * 4];
            float av[8] = {a0.x, a0.y, a0.z, a0.w, a1.x, a1.y, a1.z, a1.w};
            float bw[8] = {b0.x, b0.y, b0.z, b0.w, b1.x, b1.y, b1.z, b1.w};
            #pragma unroll
            for (int i = 0; i < 8; ++i)
                #pragma unroll
                for (int j = 0; j < 8; ++j)
                    acc[i][j] = fmaf(av[i], bw[j], acc[i][j]);
        }
    }

    #pragma unroll
    for (int ri = 0; ri < 2; ++ri) {
        #pragma unroll
        for (int i = 0; i < 4; ++i) {
            int r = r0 + ri * 64 + ty * 4 + i;
            #pragma unroll
            for (int ci = 0; ci < 2; ++ci) {
                int n = n0 + ci * 64 + tx * 4;
                float4 o;
                o.x = acc[ri * 4 + i][ci * 4 + 0] + bo[n + 0];
                o.y = acc[ri * 4 + i][ci * 4 + 1] + bo[n + 1];
                o.z = acc[ri * 4 + i][ci * 4 + 2] + bo[n + 2];
                o.w = acc[ri * 4 + i][ci * 4 + 3] + bo[n + 3];
                *(float4*)&out[(size_t)r * DD + n] = o;
            }
        }
    }
}

// ---------------------------------------------------------------
extern "C" void kernel_launch(void* const* d_in, const int* in_sizes, int n_in,
                              void* d_out, int out_size, void* d_ws, size_t ws_size,
                              hipStream_t stream)
{
    const float* x  = (const float*)d_in[0];
    const float* Wq = (const float*)d_in[1];
    const float* bq = (const float*)d_in[2];
    const float* Wk = (const float*)d_in[3];
    const float* bk = (const float*)d_in[4];
    const float* Wv = (const float*)d_in[5];
    const float* bv = (const float*)d_in[6];
    const float* Wo = (const float*)d_in[7];
    const float* bo = (const float*)d_in[8];
    float* out = (float*)d_out;
    char* ws = (char*)d_ws;

    // Workspace layout (bytes):
    float* inter = (float*)(ws);                         // 16,777,216
    float* cos_t = (float*)(ws + 16777216);              //    262,144
    float* sin_t = (float*)(ws + 17039360);              //    262,144
    unsigned short* qm = (unsigned short*)(ws + 17301504);  // 8,388,608
    unsigned short* km = (unsigned short*)(ws + 25690112);  // 8,388,608
    unsigned short* vt = (unsigned short*)(ws + 34078720);  // 8,388,608
    // total 42,467,328 bytes

    rope_table_kernel<<<dim3(256), dim3(256), 0, stream>>>(cos_t, sin_t);
    qkv_rope_kernel<<<dim3(12, 64), dim3(256), 0, stream>>>(
        x, Wq, bq, Wk, bk, Wv, bv, cos_t, sin_t, qm, km, vt);
    attn_mfma_kernel<<<dim3(16, HH, BB * LL), dim3(256), 0, stream>>>(qm, km, vt, inter);
    outproj_kernel<<<dim3(4, 64), dim3(256), 0, stream>>>(inter, Wo, bo, out);
}

// Round 3
// 210.175 us; speedup vs baseline: 4.2041x; 1.7807x over previous
//
#include <hip/hip_runtime.h>
#include <math.h>

#define BB 2
#define LL 2
#define SS 2048
#define DD 512
#define HH 8
#define DHH 64

typedef __attribute__((ext_vector_type(8))) short bf16x8;
typedef __attribute__((ext_vector_type(4))) float f32x4;

#define MFMA16(a, b, c) __builtin_amdgcn_mfma_f32_16x16x32_bf16((a), (b), (c), 0, 0, 0)

__device__ __forceinline__ unsigned short f2bf(float f) {
    union { float f; unsigned u; } x; x.f = f;
    unsigned u = x.u;
    return (unsigned short)((u + 0x7fffu + ((u >> 16) & 1u)) >> 16);
}

__device__ __forceinline__ void gload16(const unsigned short* g, unsigned short* l) {
    __builtin_amdgcn_global_load_lds(
        (const __attribute__((address_space(1))) unsigned int*)g,
        (__attribute__((address_space(3))) unsigned int*)l, 16, 0, 0);
}

// ---------------------------------------------------------------
// K0: RoPE table (fp64 -> fp32). 2048 positions x 32 freqs.
// ---------------------------------------------------------------
__global__ void rope_table_kernel(float* __restrict__ cos_t, float* __restrict__ sin_t) {
    int idx = blockIdx.x * 256 + threadIdx.x;
    if (idx >= SS * 32) return;
    int s = idx >> 5;
    int f = idx & 31;
    double inv = pow(10000.0, -(double)(2 * f) / (double)DHH);
    double ang = (double)s * inv;
    cos_t[idx] = (float)cos(ang);
    sin_t[idx] = (float)sin(ang);
}

// ---------------------------------------------------------------
// K0b: fp32 -> bf16 convert of x, Wq, Wk, Wv, Wo into one contiguous
// bf16 region (xb | wqb | wkb | wvb | wob).
// ---------------------------------------------------------------
__global__ __launch_bounds__(256) void convert_kernel(
    const float* __restrict__ x,  const float* __restrict__ wq,
    const float* __restrict__ wk, const float* __restrict__ wv,
    const float* __restrict__ wo, unsigned short* __restrict__ dst)
{
    int i = blockIdx.x * 256 + threadIdx.x;   // float4 index, 0..1310719
    const float* src;
    int local;
    if (i < 1048576)      { src = x;  local = i; }
    else if (i < 1114112) { src = wq; local = i - 1048576; }
    else if (i < 1179648) { src = wk; local = i - 1114112; }
    else if (i < 1245184) { src = wv; local = i - 1179648; }
    else                  { src = wo; local = i - 1245184; }
    float4 v = ((const float4*)src)[local];
    ushort4 o;
    o.x = f2bf(v.x); o.y = f2bf(v.y); o.z = f2bf(v.z); o.w = f2bf(v.w);
    *(ushort4*)&dst[(size_t)i * 4] = o;
}

// ---------------------------------------------------------------
// K1: QKV projection, bf16 MFMA. m97-style tile: BM=BN=128, BK=32,
// 4 waves (2x2 of 64x64), global_load_lds width 16.
//   mat 0: q = x*Wq^T + bq -> rope -> *1/sqrt(512) -> qm [bl,h,s,dh]
//   mat 1: k = x*Wk^T + bk  (attn V) -> vt [bl,h,dh,s]  (operands swapped:
//          A=W, B=X, so C^T layout gives coalesced transposed stores)
//   mat 2: v = x*Wv^T + bv -> rope -> km [bl,h,s,dh]   (attn K)
// ---------------------------------------------------------------
__global__ __launch_bounds__(256) void qkv_mfma_kernel(
    const unsigned short* __restrict__ xb,
    const unsigned short* __restrict__ wqb,
    const unsigned short* __restrict__ wkb,
    const unsigned short* __restrict__ wvb,
    const float* __restrict__ bq, const float* __restrict__ bk,
    const float* __restrict__ bv,
    const float* __restrict__ cos_t, const float* __restrict__ sin_t,
    unsigned short* __restrict__ qm, unsigned short* __restrict__ km,
    unsigned short* __restrict__ vt)
{
    __shared__ __align__(16) unsigned short As[4096];   // [row][32] row-major
    __shared__ __align__(16) unsigned short Bs[4096];

    const int tid  = threadIdx.x;
    const int w    = tid >> 6;
    const int lane = tid & 63;
    const int c    = lane & 15;
    const int quad = lane >> 4;
    const int mw   = (w & 1) * 64;
    const int nw   = (w >> 1) * 64;

    const int bx    = blockIdx.x;        // 0..11
    const int mat   = bx >> 2;
    const int nloc0 = (bx & 3) * 128;    // col tile within this matrix
    const int row0  = blockIdx.y * 128;  // x-row tile

    const unsigned short* wsel = (mat == 0) ? wqb : (mat == 1) ? wkb : wvb;
    const float* bsel          = (mat == 0) ? bq  : (mat == 1) ? bk  : bv;

    const unsigned short* aSrc = (mat == 1) ? (wsel + (size_t)nloc0 * DD)
                                            : (xb   + (size_t)row0  * DD);
    const unsigned short* bSrc = (mat == 1) ? (xb   + (size_t)row0  * DD)
                                            : (wsel + (size_t)nloc0 * DD);

    f32x4 acc[4][4];
    #pragma unroll
    for (int i = 0; i < 4; ++i)
        #pragma unroll
        for (int j = 0; j < 4; ++j)
            #pragma unroll
            for (int r = 0; r < 4; ++r) acc[i][j][r] = 0.f;

    for (int k0 = 0; k0 < DD; k0 += 32) {
        __syncthreads();
        #pragma unroll
        for (int it = 0; it < 2; ++it) {
            int L   = it * 2048 + w * 512 + lane * 8;   // elem index in tile
            int row = L >> 5;
            int k   = L & 31;
            gload16(aSrc + (size_t)row * DD + k0 + k, &As[L]);
            gload16(bSrc + (size_t)row * DD + k0 + k, &Bs[L]);
        }
        __syncthreads();
        bf16x8 af[4], bfr[4];
        #pragma unroll
        for (int mt = 0; mt < 4; ++mt)
            af[mt] = *(const bf16x8*)&As[(mw + mt * 16 + c) * 32 + quad * 8];
        #pragma unroll
        for (int nt = 0; nt < 4; ++nt)
            bfr[nt] = *(const bf16x8*)&Bs[(nw + nt * 16 + c) * 32 + quad * 8];
        #pragma unroll
        for (int mt = 0; mt < 4; ++mt)
            #pragma unroll
            for (int nt = 0; nt < 4; ++nt)
                acc[mt][nt] = MFMA16(af[mt], bfr[nt], acc[mt][nt]);
    }

    if (mat == 1) {
        // C^T layout: m (quad*4+reg) = weight row -> (h,dh); n (c) = x row -> s
        #pragma unroll
        for (int mt = 0; mt < 4; ++mt) {
            #pragma unroll
            for (int nt = 0; nt < 4; ++nt) {
                int xr = row0 + nw + nt * 16 + c;
                int bl = xr >> 11, s = xr & 2047;
                #pragma unroll
                for (int r = 0; r < 4; ++r) {
                    int col = nloc0 + mw + mt * 16 + quad * 4 + r;
                    int h = col >> 6, dh = col & 63;
                    float v = acc[mt][nt][r] + bsel[col];
                    vt[((size_t)(bl * HH + h) * DHH + dh) * SS + s] = f2bf(v);
                }
            }
        }
    } else {
        unsigned short* dst = (mat == 0) ? qm : km;
        const float qscale = (mat == 0) ? 0.04419417382415922f : 1.0f;
        #pragma unroll
        for (int mt = 0; mt < 4; ++mt) {
            #pragma unroll
            for (int r = 0; r < 4; ++r) {
                int xr = row0 + mw + mt * 16 + quad * 4 + r;
                int bl = xr >> 11, s = xr & 2047;
                #pragma unroll
                for (int nt = 0; nt < 4; ++nt) {
                    int col = nloc0 + nw + nt * 16 + c;
                    int h = col >> 6, dh = col & 63;
                    float v = acc[mt][nt][r] + bsel[col];
                    float pv = __shfl_xor(v, 1);
                    int f = dh >> 1;
                    float cs = cos_t[s * 32 + f], sn = sin_t[s * 32 + f];
                    float o = (dh & 1) ? fmaf(v, cs, pv * sn)
                                       : fmaf(v, cs, -(pv * sn));
                    dst[((size_t)(bl * HH + h) * SS + s) * DHH + dh] = f2bf(o * qscale);
                }
            }
        }
    }
}

// ---------------------------------------------------------------
// K2: causal flash attention, bf16 MFMA (16x16x32).
// Br=128, Bc=64; softmax without max-subtraction (scores bounded);
// O^T = V^T P^T; l via ones-row MFMA. Writes inter as bf16.
// ---------------------------------------------------------------
#define S_KV 72
#define S_P  72

__global__ __launch_bounds__(256) void attn_mfma_kernel(
    const unsigned short* __restrict__ qm,
    const unsigned short* __restrict__ km,
    const unsigned short* __restrict__ vt,
    unsigned short* __restrict__ inter)
{
    __shared__ unsigned short Ks[64 * S_KV];   // [key][dh]
    __shared__ unsigned short Vt[64 * S_KV];   // [dh][key]
    __shared__ unsigned short Ps[128 * S_P];   // [q_local][key], wave-private rows

    const int tid  = threadIdx.x;
    const int w    = tid >> 6;
    const int lane = tid & 63;
    const int c    = lane & 15;
    const int quad = lane >> 4;

    const int qt = (gridDim.x - 1) - blockIdx.x;   // heavy blocks first
    const int h  = blockIdx.y;
    const int bl = blockIdx.z;
    const int q0 = qt * 128;
    const int qw = q0 + w * 32;

    const size_t seq_base = (size_t)(bl * HH + h) * SS * DHH;
    const size_t vt_base  = (size_t)(bl * HH + h) * DHH * SS;

    bf16x8 qf[2][2];
    #pragma unroll
    for (int mt = 0; mt < 2; ++mt)
        #pragma unroll
        for (int kk = 0; kk < 2; ++kk)
            qf[mt][kk] = *(const bf16x8*)(qm + seq_base +
                (size_t)(qw + mt * 16 + c) * DHH + kk * 32 + quad * 8);

    f32x4 oacc[4][2];
    f32x4 lacc[2];
    #pragma unroll
    for (int i = 0; i < 4; ++i)
        #pragma unroll
        for (int j = 0; j < 2; ++j)
            #pragma unroll
            for (int r = 0; r < 4; ++r) oacc[i][j][r] = 0.f;
    #pragma unroll
    for (int j = 0; j < 2; ++j)
        #pragma unroll
        for (int r = 0; r < 4; ++r) lacc[j][r] = 0.f;

    bf16x8 ones;
    #pragma unroll
    for (int i = 0; i < 8; ++i) ones[i] = (short)0x3F80;

    const int ntiles = 2 * qt + 2;
    for (int kt = 0; kt < ntiles; ++kt) {
        __syncthreads();
        {
            const unsigned short* kg = km + seq_base + (size_t)(kt * 64) * DHH;
            const unsigned short* vg = vt + vt_base + kt * 64;
            #pragma unroll
            for (int it = 0; it < 2; ++it) {
                int idx = tid + it * 256;
                int row = idx >> 3, ch = idx & 7;
                *(bf16x8*)&Ks[row * S_KV + ch * 8] = *(const bf16x8*)(kg + idx * 8);
                *(bf16x8*)&Vt[row * S_KV + ch * 8] =
                    *(const bf16x8*)(vg + (size_t)row * SS + ch * 8);
            }
        }
        __syncthreads();

        if (64 * kt <= qw + 31) {
            f32x4 sacc[2][4];
            #pragma unroll
            for (int mt = 0; mt < 2; ++mt)
                #pragma unroll
                for (int nt = 0; nt < 4; ++nt)
                    #pragma unroll
                    for (int r = 0; r < 4; ++r) sacc[mt][nt][r] = 0.f;
            #pragma unroll
            for (int kk = 0; kk < 2; ++kk) {
                bf16x8 bk_[4];
                #pragma unroll
                for (int nt = 0; nt < 4; ++nt)
                    bk_[nt] = *(const bf16x8*)&Ks[(nt * 16 + c) * S_KV + kk * 32 + quad * 8];
                #pragma unroll
                for (int mt = 0; mt < 2; ++mt)
                    #pragma unroll
                    for (int nt = 0; nt < 4; ++nt)
                        sacc[mt][nt] = MFMA16(qf[mt][kk], bk_[nt], sacc[mt][nt]);
            }

            const bool need_mask = (64 * kt + 63 > qw);
            #pragma unroll
            for (int mt = 0; mt < 2; ++mt) {
                #pragma unroll
                for (int r = 0; r < 4; ++r) {
                    int prow = w * 32 + mt * 16 + quad * 4 + r;
                    int qrow = qw + mt * 16 + quad * 4 + r;
                    unsigned short* pp = &Ps[prow * S_P + c];
                    #pragma unroll
                    for (int nt = 0; nt < 4; ++nt) {
                        float p = __expf(sacc[mt][nt][r]);
                        if (need_mask && (64 * kt + nt * 16 + c > qrow)) p = 0.f;
                        pp[nt * 16] = f2bf(p);
                    }
                }
            }

            #pragma unroll
            for (int kk = 0; kk < 2; ++kk) {
                bf16x8 bp0 = *(const bf16x8*)&Ps[(w * 32 + c) * S_P + kk * 32 + quad * 8];
                bf16x8 bp1 = *(const bf16x8*)&Ps[(w * 32 + 16 + c) * S_P + kk * 32 + quad * 8];
                lacc[0] = MFMA16(ones, bp0, lacc[0]);
                lacc[1] = MFMA16(ones, bp1, lacc[1]);
                #pragma unroll
                for (int mt4 = 0; mt4 < 4; ++mt4) {
                    bf16x8 av = *(const bf16x8*)&Vt[(mt4 * 16 + c) * S_KV + kk * 32 + quad * 8];
                    oacc[mt4][0] = MFMA16(av, bp0, oacc[mt4][0]);
                    oacc[mt4][1] = MFMA16(av, bp1, oacc[mt4][1]);
                }
            }
        }
    }

    float invl0 = 1.f / lacc[0][0];
    float invl1 = 1.f / lacc[1][0];
    #pragma unroll
    for (int mt4 = 0; mt4 < 4; ++mt4) {
        int dh0 = mt4 * 16 + quad * 4;
        #pragma unroll
        for (int nt2 = 0; nt2 < 2; ++nt2) {
            int query = qw + nt2 * 16 + c;
            float il = nt2 ? invl1 : invl0;
            ushort4 o;
            o.x = f2bf(oacc[mt4][nt2][0] * il);
            o.y = f2bf(oacc[mt4][nt2][1] * il);
            o.z = f2bf(oacc[mt4][nt2][2] * il);
            o.w = f2bf(oacc[mt4][nt2][3] * il);
            *(ushort4*)&inter[((size_t)bl * SS + query) * DD + h * DHH + dh0] = o;
        }
    }
}

// ---------------------------------------------------------------
// K3: output projection, bf16 MFMA:  out = inter_bf * Wo^T + bo (fp32 out)
// ---------------------------------------------------------------
__global__ __launch_bounds__(256) void outproj_mfma_kernel(
    const unsigned short* __restrict__ ib,
    const unsigned short* __restrict__ wob,
    const float* __restrict__ bo, float* __restrict__ out)
{
    __shared__ __align__(16) unsigned short As[4096];
    __shared__ __align__(16) unsigned short Bs[4096];

    const int tid  = threadIdx.x;
    const int w    = tid >> 6;
    const int lane = tid & 63;
    const int c    = lane & 15;
    const int quad = lane >> 4;
    const int mw   = (w & 1) * 64;
    const int nw   = (w >> 1) * 64;

    const int n0   = blockIdx.x * 128;
    const int row0 = blockIdx.y * 128;

    const unsigned short* aSrc = ib  + (size_t)row0 * DD;
    const unsigned short* bSrc = wob + (size_t)n0   * DD;

    f32x4 acc[4][4];
    #pragma unroll
    for (int i = 0; i < 4; ++i)
        #pragma unroll
        for (int j = 0; j < 4; ++j)
            #pragma unroll
            for (int r = 0; r < 4; ++r) acc[i][j][r] = 0.f;

    for (int k0 = 0; k0 < DD; k0 += 32) {
        __syncthreads();
        #pragma unroll
        for (int it = 0; it < 2; ++it) {
            int L   = it * 2048 + w * 512 + lane * 8;
            int row = L >> 5;
            int k   = L & 31;
            gload16(aSrc + (size_t)row * DD + k0 + k, &As[L]);
            gload16(bSrc + (size_t)row * DD + k0 + k, &Bs[L]);
        }
        __syncthreads();
        bf16x8 af[4], bfr[4];
        #pragma unroll
        for (int mt = 0; mt < 4; ++mt)
            af[mt] = *(const bf16x8*)&As[(mw + mt * 16 + c) * 32 + quad * 8];
        #pragma unroll
        for (int nt = 0; nt < 4; ++nt)
            bfr[nt] = *(const bf16x8*)&Bs[(nw + nt * 16 + c) * 32 + quad * 8];
        #pragma unroll
        for (int mt = 0; mt < 4; ++mt)
            #pragma unroll
            for (int nt = 0; nt < 4; ++nt)
                acc[mt][nt] = MFMA16(af[mt], bfr[nt], acc[mt][nt]);
    }

    #pragma unroll
    for (int mt = 0; mt < 4; ++mt) {
        #pragma unroll
        for (int r = 0; r < 4; ++r) {
            int xr = row0 + mw + mt * 16 + quad * 4 + r;
            #pragma unroll
            for (int nt = 0; nt < 4; ++nt) {
                int col = n0 + nw + nt * 16 + c;
                out[(size_t)xr * DD + col] = acc[mt][nt][r] + bo[col];
            }
        }
    }
}

// ---------------------------------------------------------------
extern "C" void kernel_launch(void* const* d_in, const int* in_sizes, int n_in,
                              void* d_out, int out_size, void* d_ws, size_t ws_size,
                              hipStream_t stream)
{
    const float* x  = (const float*)d_in[0];
    const float* Wq = (const float*)d_in[1];
    const float* bq = (const float*)d_in[2];
    const float* Wk = (const float*)d_in[3];
    const float* bk = (const float*)d_in[4];
    const float* Wv = (const float*)d_in[5];
    const float* bv = (const float*)d_in[6];
    const float* Wo = (const float*)d_in[7];
    const float* bo = (const float*)d_in[8];
    float* out = (float*)d_out;
    char* ws = (char*)d_ws;

    // Workspace layout (bytes):
    unsigned short* inter = (unsigned short*)(ws);             //  8,388,608
    float* cos_t = (float*)(ws + 8388608);                     //    262,144
    float* sin_t = (float*)(ws + 8650752);                     //    262,144
    unsigned short* xb  = (unsigned short*)(ws + 8912896);     //  8,388,608
    unsigned short* wqb = (unsigned short*)(ws + 17301504);    //    524,288
    unsigned short* wkb = (unsigned short*)(ws + 17825792);    //    524,288
    unsigned short* wvb = (unsigned short*)(ws + 18350080);    //    524,288
    unsigned short* wob = (unsigned short*)(ws + 18874368);    //    524,288
    unsigned short* qm  = (unsigned short*)(ws + 19398656);    //  8,388,608
    unsigned short* km  = (unsigned short*)(ws + 27787264);    //  8,388,608
    unsigned short* vt  = (unsigned short*)(ws + 36175872);    //  8,388,608
    // total 44,564,480 bytes

    rope_table_kernel<<<dim3(256), dim3(256), 0, stream>>>(cos_t, sin_t);
    convert_kernel<<<dim3(5120), dim3(256), 0, stream>>>(x, Wq, Wk, Wv, Wo, xb);
    qkv_mfma_kernel<<<dim3(12, 64), dim3(256), 0, stream>>>(
        xb, wqb, wkb, wvb, bq, bk, bv, cos_t, sin_t, qm, km, vt);
    attn_mfma_kernel<<<dim3(16, HH, BB * LL), dim3(256), 0, stream>>>(qm, km, vt, inter);
    outproj_mfma_kernel<<<dim3(4, 64), dim3(256), 0, stream>>>(inter, wob, bo, out);
}